// Round 1
// 1422.064 us; speedup vs baseline: 2.7168x; 2.7168x over previous
//
#include <hip/hip_runtime.h>

// ALSH Conv: hash-table init + vote + mask + masked 3x3 conv via split-bf16 MFMA.
// x: [32,64,128,128] f32, kernels: [256,64,3,3] f32, a: [8,67,3,3] f32, b: [8] f32
// out: [32,256,128,128] f32. R=4, U=0.99, table=512.

#define NCH 64
#define OCH 256
#define HNUM 8
#define IMG 128
#define IMG2 (IMG * IMG)
#define TSZ 512
#define KROW 576      // 64*9
#define AROW 603      // 67*9
#define MPOW 27

typedef unsigned short u16;
typedef __attribute__((ext_vector_type(8))) __bf16 bf16x8;
typedef __attribute__((ext_vector_type(16))) float f32x16;
typedef __attribute__((ext_vector_type(4))) unsigned int u32x4;

__device__ __forceinline__ u16 f2bf_rne(float f) {
  union { float f; unsigned u; } c; c.f = f;
  return (u16)((c.u + 0x7FFFu + ((c.u >> 16) & 1u)) >> 16);
}
__device__ __forceinline__ void split_bf16(float v, u16& h, u16& l) {
  u16 hu = f2bf_rne(v);
  union { unsigned u; float f; } d; d.u = ((unsigned)hu) << 16;
  h = hu;
  l = f2bf_rne(v - d.f);
}

// ---------------- K1: row norms, scale, zero counts ----------------
__global__ __launch_bounds__(256) void k_norms(
    const float* __restrict__ kernels, float* __restrict__ norms,
    float* __restrict__ scale_out, int* __restrict__ counts) {
  int o = threadIdx.x;
  const float* row = kernels + (size_t)o * KROW;
  float s = 0.f;
  for (int i = 0; i < KROW; i++) { float v = row[i]; s = fmaf(v, v, s); }
  float nrm = sqrtf(s);
  norms[o] = nrm;
  __shared__ float red[256];
  red[o] = nrm;
  __syncthreads();
  for (int st = 128; st > 0; st >>= 1) {
    if (o < st) red[o] = fmaxf(red[o], red[o + st]);
    __syncthreads();
  }
  if (o == 0) scale_out[0] = 0.99f / red[0];
  for (int i = o; i < HNUM * TSZ; i += 256) counts[i] = 0;
}

// ---------------- K2: kernel buckets under each hash ----------------
__global__ __launch_bounds__(256) void k_table(
    const float* __restrict__ kernels, const float* __restrict__ a,
    const float* __restrict__ b, const float* __restrict__ scale_p,
    int* __restrict__ kbuck) {
  int h = blockIdx.x;     // 0..7
  int o = threadIdx.x;    // 0..255
  float scale = *scale_p;
  const float* ar = a + (size_t)h * AROW;
  const float* kr = kernels + (size_t)o * KROW;
  float dot = 0.f, s2 = 0.f;
  for (int i = 0; i < KROW; i++) {
    float sv = scale * kr[i];
    dot = fmaf(ar[i], sv, dot);
    s2 = fmaf(sv, sv, s2);
  }
  float p = sqrtf(s2);                 // sn = ||scaled row||
  for (int j = 1; j <= MPOW; j++) {    // powers sn^(2^j)
    p = p * p;
    dot = fmaf(ar[KROW - 1 + j], p, dot);
  }
  float v = floorf((dot + b[h]) * 0.25f);
  v = fabsf(fmodf(v, (float)TSZ));
  kbuck[h * OCH + o] = (int)v;
}

// ---------------- K3: vote conv + histogram ----------------
__global__ __launch_bounds__(256) void k_vote(
    const float* __restrict__ x, const float* __restrict__ a,
    const float* __restrict__ b, int* __restrict__ counts) {
  int tid = threadIdx.x;
  int tx0 = blockIdx.x << 4, ty0 = blockIdx.y << 4;
  int n = blockIdx.z;
  int lx = tid & 15, ly = tid >> 4;

  __shared__ float tile_s[18 * 18];
  __shared__ int hist[HNUM * TSZ];
  for (int i = tid; i < HNUM * TSZ; i += 256) hist[i] = 0;

  float acc[HNUM] = {0, 0, 0, 0, 0, 0, 0, 0};
  const float* xn = x + (size_t)n * NCH * IMG2;

  for (int c = 0; c < 67; c++) {
    __syncthreads();
    for (int i = tid; i < 324; i += 256) {
      int yy = ty0 + i / 18 - 1;
      int xx = tx0 + i % 18 - 1;
      float v = 0.0f;
      if ((unsigned)yy < (unsigned)IMG && (unsigned)xx < (unsigned)IMG)
        v = (c < NCH) ? xn[(size_t)c * IMG2 + yy * IMG + xx] : 0.5f;
      tile_s[i] = v;
    }
    __syncthreads();
    float t[9];
#pragma unroll
    for (int dy = 0; dy < 3; dy++)
#pragma unroll
      for (int dx = 0; dx < 3; dx++)
        t[dy * 3 + dx] = tile_s[(ly + dy) * 18 + lx + dx];
#pragma unroll
    for (int h = 0; h < HNUM; h++) {
      const float* ww = a + (size_t)(h * 67 + c) * 9;  // uniform -> s_load
      float s = acc[h];
#pragma unroll
      for (int k = 0; k < 9; k++) s = fmaf(t[k], ww[k], s);
      acc[h] = s;
    }
  }
  __syncthreads();
#pragma unroll
  for (int h = 0; h < HNUM; h++) {
    float v = floorf((acc[h] + b[h]) * 0.25f);
    v = fabsf(fmodf(v, (float)TSZ));
    atomicAdd(&hist[(h << 9) + (int)v], 1);
  }
  __syncthreads();
  for (int i = tid; i < HNUM * TSZ; i += 256) {
    int c = hist[i];
    if (c) atomicAdd(&counts[i], c);
  }
}

// ---------------- K4: argmax per hash + mask (as float 0/1) ----------------
__global__ __launch_bounds__(512) void k_mask(
    const int* __restrict__ counts, const int* __restrict__ kbuck,
    float* __restrict__ maskf) {
  int tid = threadIdx.x;
  __shared__ int sv[HNUM];
  int h = tid >> 6, lane = tid & 63;
  // argmax with first-max tie-break: key = count*1024 + (511 - idx), count<2^20
  int best = -1;
  for (int i = lane; i < TSZ; i += 64) {
    int key = (counts[h * TSZ + i] << 10) | (TSZ - 1 - i);
    if (key > best) best = key;
  }
  for (int off = 32; off > 0; off >>= 1) {
    int other = __shfl_xor(best, off);
    if (other > best) best = other;
  }
  if (lane == 0) sv[h] = (TSZ - 1) - (best & 1023);
  __syncthreads();
  if (tid < OCH) {
    int m = 0;
    for (int hh = 0; hh < HNUM; hh++) {
      int kv = kbuck[hh * OCH + tid];
#pragma unroll
      for (int j = 0; j < HNUM; j++) m |= (kv == sv[j]) ? 1 : 0;
    }
    maskf[tid] = m ? 1.0f : 0.0f;
  }
}

// ---------------- K4b: weight transform -> [tap][o][c] split hi/lo bf16 ----
__global__ __launch_bounds__(64) void k_wt(
    const float* __restrict__ kernels, u16* __restrict__ wt_hi,
    u16* __restrict__ wt_lo) {
  int o = blockIdx.x;      // 0..255
  int c = threadIdx.x;     // 0..63
  const float* kr = kernels + (size_t)o * KROW + (size_t)c * 9;
#pragma unroll
  for (int tap = 0; tap < 9; tap++) {
    float v = kr[tap];
    u16 h, l;
    split_bf16(v, h, l);
    size_t idx = ((size_t)tap * OCH + o) * NCH + c;
    wt_hi[idx] = h;
    wt_lo[idx] = l;
  }
}

// ---------------- K5: masked 3x3 conv as implicit GEMM on MFMA ----------------
// Block: 256 thr = 4 waves (2 och-halves x 2 rows). Out tile: 128 och x (2 rows x 64 cols).
// A-operand = weights (M=och), B-operand = pixels (N=px) -> coalesced stores.
// Split bf16: out = Wh*Xh + Wh*Xl + Wl*Xh (fp32 accum).
// LDS: X tile [4 rows][66 cols][64 ch] hi+lo bf16, 16B-slot swizzled; staged ONCE,
// K-loop (9 taps x 2 ch-halves) has NO barriers.
#define XCOLS 66
#define XBYTES (4 * XCOLS * NCH * 2)   // 33792 per buffer
#define LOOFF (XBYTES / 16)            // 2112 u32x4

__global__ __launch_bounds__(256, 2) void k_conv_mfma(
    const float* __restrict__ x, const u16* __restrict__ wt_hi,
    const u16* __restrict__ wt_lo, const float* __restrict__ maskf,
    float* __restrict__ out) {
  __shared__ u32x4 xs[2 * LOOFF];
  __shared__ float smaskf[OCH];

  int tid = threadIdx.x;
  int lane = tid & 63, wid = tid >> 6;
  int l31 = lane & 31, lh = lane >> 5;
  int wm = wid >> 1;      // och half within block (0..1)
  int wp = wid & 1;       // image row within pair (0..1)

  int nt = blockIdx.x;    // och tile (0..1)
  int py = blockIdx.y;    // 0..127: (rowpair 0..63) | (colhalf<<6)
  int n = blockIdx.z;     // batch
  int y0 = (py & 63) * 2;
  int x0 = (py >> 6) * 64;

  // ---- stage X: 4 rows x 66 cols x 64 ch, split hi/lo bf16, swizzled b128 ----
  const float* xn = x + (size_t)n * NCH * IMG2;
  for (int i = tid; i < 4 * XCOLS; i += 256) {
    int r = i / XCOLS, col = i - r * XCOLS;
    int yy = y0 - 1 + r, xx = x0 - 1 + col;
    bool ok = ((unsigned)yy < (unsigned)IMG) & ((unsigned)xx < (unsigned)IMG);
    const float* src = xn + ((size_t)(ok ? yy : 0) * IMG + (ok ? xx : 0));
    int rowbase = i * 128;
#pragma unroll
    for (int co = 0; co < NCH; co += 8) {
      u32x4 hv, lv;
#pragma unroll
      for (int q = 0; q < 4; q++) {
        float v0 = ok ? src[(size_t)(co + 2 * q) * IMG2] : 0.f;
        float v1 = ok ? src[(size_t)(co + 2 * q + 1) * IMG2] : 0.f;
        u16 h0, l0, h1, l1;
        split_bf16(v0, h0, l0);
        split_bf16(v1, h1, l1);
        hv[q] = (unsigned)h0 | ((unsigned)h1 << 16);
        lv[q] = (unsigned)l0 | ((unsigned)l1 << 16);
      }
      int slot = (((co >> 3) ^ (col & 7)) + ((col >> 3) << 1)) & 7;
      int idx = (rowbase + slot * 16) >> 4;
      xs[idx] = hv;
      xs[idx + LOOFF] = lv;
    }
  }
  for (int i = tid; i < OCH; i += 256) smaskf[i] = maskf[i];
  __syncthreads();

  // ---- per-lane weight row pointers (A-operand: och = base + l31 + mi*32) ----
  int ochb = nt * 128 + wm * 64;
  const u16* pwh0 = wt_hi + (size_t)(ochb + l31) * NCH;
  const u16* pwh1 = wt_hi + (size_t)(ochb + 32 + l31) * NCH;
  const u16* pwl0 = wt_lo + (size_t)(ochb + l31) * NCH;
  const u16* pwl1 = wt_lo + (size_t)(ochb + 32 + l31) * NCH;

  f32x16 acc00 = (f32x16)0.0f, acc01 = (f32x16)0.0f;
  f32x16 acc10 = (f32x16)0.0f, acc11 = (f32x16)0.0f;

  for (int dy = 0; dy < 3; dy++) {
    int rb = (wp + dy) * XCOLS;
#pragma unroll
    for (int dx = 0; dx < 3; dx++) {
      int tap = dy * 3 + dx;
      size_t tof = (size_t)tap * (OCH * NCH);
      int colA = l31 + dx, colB = colA + 32;
      int baseA = (rb + colA) * 128, baseB = (rb + colB) * 128;
      int sxA = colA & 7, shA = (colA >> 3) << 1;
      int sxB = colB & 7, shB = (colB >> 3) << 1;
#pragma unroll
      for (int s = 0; s < 2; s++) {
#pragma unroll
        for (int kk = 0; kk < 2; kk++) {
          int cw = s * 32 + kk * 16 + lh * 8;
          int slot = s * 4 + kk * 2 + lh;
          bf16x8 w0h = *(const bf16x8*)(pwh0 + tof + cw);
          bf16x8 w1h = *(const bf16x8*)(pwh1 + tof + cw);
          bf16x8 w0l = *(const bf16x8*)(pwl0 + tof + cw);
          bf16x8 w1l = *(const bf16x8*)(pwl1 + tof + cw);
          int iA = (baseA + ((((slot ^ sxA) + shA) & 7) << 4)) >> 4;
          int iB = (baseB + ((((slot ^ sxB) + shB) & 7) << 4)) >> 4;
          bf16x8 xAh = __builtin_bit_cast(bf16x8, xs[iA]);
          bf16x8 xAl = __builtin_bit_cast(bf16x8, xs[iA + LOOFF]);
          bf16x8 xBh = __builtin_bit_cast(bf16x8, xs[iB]);
          bf16x8 xBl = __builtin_bit_cast(bf16x8, xs[iB + LOOFF]);
          acc00 = __builtin_amdgcn_mfma_f32_32x32x16_bf16(w0h, xAh, acc00, 0, 0, 0);
          acc01 = __builtin_amdgcn_mfma_f32_32x32x16_bf16(w0h, xBh, acc01, 0, 0, 0);
          acc10 = __builtin_amdgcn_mfma_f32_32x32x16_bf16(w1h, xAh, acc10, 0, 0, 0);
          acc11 = __builtin_amdgcn_mfma_f32_32x32x16_bf16(w1h, xBh, acc11, 0, 0, 0);
          acc00 = __builtin_amdgcn_mfma_f32_32x32x16_bf16(w0h, xAl, acc00, 0, 0, 0);
          acc01 = __builtin_amdgcn_mfma_f32_32x32x16_bf16(w0h, xBl, acc01, 0, 0, 0);
          acc10 = __builtin_amdgcn_mfma_f32_32x32x16_bf16(w1h, xAl, acc10, 0, 0, 0);
          acc11 = __builtin_amdgcn_mfma_f32_32x32x16_bf16(w1h, xBl, acc11, 0, 0, 0);
          acc00 = __builtin_amdgcn_mfma_f32_32x32x16_bf16(w0l, xAh, acc00, 0, 0, 0);
          acc01 = __builtin_amdgcn_mfma_f32_32x32x16_bf16(w0l, xBh, acc01, 0, 0, 0);
          acc10 = __builtin_amdgcn_mfma_f32_32x32x16_bf16(w1l, xAh, acc10, 0, 0, 0);
          acc11 = __builtin_amdgcn_mfma_f32_32x32x16_bf16(w1l, xBh, acc11, 0, 0, 0);
        }
      }
    }
  }

  // ---- masked store: D col = lane&31 = pixel, row = (reg&3)+8*(reg>>2)+4*lh = och ----
  float* outp = out + (size_t)n * OCH * IMG2;
  int yy = y0 + wp;
#pragma unroll
  for (int mi = 0; mi < 2; mi++) {
    int ob = ochb + mi * 32 + 4 * lh;
#pragma unroll
    for (int reg = 0; reg < 16; reg++) {
      int och = ob + (reg & 3) + 8 * (reg >> 2);
      float mv = smaskf[och];
      size_t rowoff = (size_t)och * IMG2 + (size_t)yy * IMG + x0 + l31;
      float vA = (mi == 0 ? acc00[reg] : acc10[reg]) * mv;
      float vB = (mi == 0 ? acc01[reg] : acc11[reg]) * mv;
      outp[rowoff] = vA;
      outp[rowoff + 32] = vB;
    }
  }
}

extern "C" void kernel_launch(void* const* d_in, const int* in_sizes, int n_in,
                              void* d_out, int out_size, void* d_ws, size_t ws_size,
                              hipStream_t stream) {
  const float* x = (const float*)d_in[0];
  const float* kernels = (const float*)d_in[1];
  const float* a = (const float*)d_in[2];
  const float* b = (const float*)d_in[3];
  float* out = (float*)d_out;

  char* ws = (char*)d_ws;
  float* norms  = (float*)(ws + 0);            // 1024 B
  float* scale  = (float*)(ws + 1024);         // 4 B
  int* kbuck    = (int*)(ws + 2048);           // 8192 B
  int* counts   = (int*)(ws + 10240);          // 16384 B
  float* maskf  = (float*)(ws + 26624);        // 1024 B
  u16* wt_hi    = (u16*)(ws + 32768);          // 294912 B
  u16* wt_lo    = (u16*)(ws + 32768 + 294912); // 294912 B (end: 622592)

  k_wt<<<dim3(OCH), dim3(64), 0, stream>>>(kernels, wt_hi, wt_lo);
  k_norms<<<dim3(1), dim3(256), 0, stream>>>(kernels, norms, scale, counts);
  k_table<<<dim3(HNUM), dim3(256), 0, stream>>>(kernels, a, b, scale, kbuck);
  k_vote<<<dim3(8, 8, 32), dim3(256), 0, stream>>>(x, a, b, counts);
  k_mask<<<dim3(1), dim3(512), 0, stream>>>(counts, kbuck, maskf);
  k_conv_mfma<<<dim3(2, 128, 32), dim3(256), 0, stream>>>(x, wt_hi, wt_lo,
                                                          maskf, out);
}

// Round 2
// 1330.823 us; speedup vs baseline: 2.9031x; 1.0686x over previous
//
#include <hip/hip_runtime.h>

// ALSH Conv: hash-table init + vote + mask + masked 3x3 conv via fp16 MFMA.
// x: [32,64,128,128] f32, kernels: [256,64,3,3] f32, a: [8,67,3,3] f32, b: [8] f32
// out: [32,256,128,128] f32. R=4, U=0.99, table=512.

#define NCH 64
#define OCH 256
#define HNUM 8
#define IMG 128
#define IMG2 (IMG * IMG)
#define TSZ 512
#define KROW 576      // 64*9
#define AROW 603      // 67*9
#define MPOW 27

typedef unsigned short u16;
typedef _Float16 f16;
typedef __attribute__((ext_vector_type(8))) _Float16 f16x8;
typedef __attribute__((ext_vector_type(16))) float f32x16;

// ---------------- K0: weight transform -> [tap][o][c] fp16; zero counts ----
__global__ __launch_bounds__(64) void k_wt(
    const float* __restrict__ kernels, f16* __restrict__ wt,
    int* __restrict__ counts, int* __restrict__ scalemax) {
  int o = blockIdx.x;      // 0..255
  int c = threadIdx.x;     // 0..63
  const float* kr = kernels + (size_t)o * KROW + (size_t)c * 9;
#pragma unroll
  for (int tap = 0; tap < 9; tap++)
    wt[((size_t)tap * OCH + o) * NCH + c] = (f16)kr[tap];
  int gid = o * 64 + c;
  if (gid < HNUM * TSZ) counts[gid] = 0;
  if (gid == 0) *scalemax = 0;
}

// ---------------- K1: row-norm max via wave-cooperative reduce ----------------
__global__ __launch_bounds__(64) void k_norms(
    const float* __restrict__ kernels, int* __restrict__ scalemax) {
  int o = blockIdx.x, lane = threadIdx.x;
  const float* row = kernels + (size_t)o * KROW;
  float s = 0.f;
  for (int i = lane; i < KROW; i += 64) { float v = row[i]; s = fmaf(v, v, s); }
  for (int off = 32; off > 0; off >>= 1) s += __shfl_xor(s, off);
  if (lane == 0) atomicMax(scalemax, __float_as_int(sqrtf(s)));  // >0: int order ok
}

// ---------------- K2: kernel buckets, one wave per (o,h) ----------------
__global__ __launch_bounds__(512) void k_table(
    const float* __restrict__ kernels, const float* __restrict__ a,
    const float* __restrict__ b, const int* __restrict__ scalemax,
    int* __restrict__ kbuck) {
  int o = blockIdx.x;
  int h = threadIdx.x >> 6, lane = threadIdx.x & 63;
  float scale = 0.99f / __int_as_float(*scalemax);
  const float* ar = a + (size_t)h * AROW;
  const float* kr = kernels + (size_t)o * KROW;
  float dot = 0.f, s2 = 0.f;
  for (int i = lane; i < KROW; i += 64) {
    float sv = scale * kr[i];
    dot = fmaf(ar[i], sv, dot);
    s2 = fmaf(sv, sv, s2);
  }
  for (int off = 32; off > 0; off >>= 1) {
    dot += __shfl_xor(dot, off);
    s2 += __shfl_xor(s2, off);
  }
  if (lane == 0) {
    float p = sqrtf(s2), d = dot;
    for (int j = 1; j <= MPOW; j++) { p = p * p; d = fmaf(ar[KROW - 1 + j], p, d); }
    float v = floorf((d + b[h]) * 0.25f);
    v = fabsf(fmodf(v, (float)TSZ));
    kbuck[h * OCH + o] = (int)v;
  }
}

// ---------------- K3: vote conv + histogram (32x32 px tiles, 4 px/thread) ----
__global__ __launch_bounds__(256) void k_vote(
    const float* __restrict__ x, const float* __restrict__ a,
    const float* __restrict__ b, int* __restrict__ counts) {
  int tid = threadIdx.x;
  int tx0 = blockIdx.x << 5, ty0 = blockIdx.y << 5;
  int n = blockIdx.z;
  int lc = (tid & 15) << 1, lr = (tid >> 4) << 1;

  __shared__ float tile_s[34 * 34];
  __shared__ int hist[HNUM * TSZ];
  for (int i = tid; i < HNUM * TSZ; i += 256) hist[i] = 0;

  float acc[HNUM][4] = {};
  const float* xn = x + (size_t)n * NCH * IMG2;

  for (int c = 0; c < 67; c++) {
    __syncthreads();
    for (int i = tid; i < 34 * 34; i += 256) {
      int yy = ty0 + i / 34 - 1;
      int xx = tx0 + i % 34 - 1;
      float v = 0.0f;
      if ((unsigned)yy < (unsigned)IMG && (unsigned)xx < (unsigned)IMG)
        v = (c < NCH) ? xn[(size_t)c * IMG2 + yy * IMG + xx] : 0.5f;
      tile_s[i] = v;
    }
    __syncthreads();
    float t[16];
#pragma unroll
    for (int dy = 0; dy < 4; dy++)
#pragma unroll
      for (int dx = 0; dx < 4; dx++)
        t[dy * 4 + dx] = tile_s[(lr + dy) * 34 + lc + dx];
#pragma unroll
    for (int h = 0; h < HNUM; h++) {
      const float* ww = a + (size_t)(h * 67 + c) * 9;  // uniform -> s_load
      float w[9];
#pragma unroll
      for (int k = 0; k < 9; k++) w[k] = ww[k];
#pragma unroll
      for (int py = 0; py < 2; py++)
#pragma unroll
        for (int px = 0; px < 2; px++) {
          float s = acc[h][py * 2 + px];
#pragma unroll
          for (int ky = 0; ky < 3; ky++)
#pragma unroll
            for (int kx = 0; kx < 3; kx++)
              s = fmaf(t[(py + ky) * 4 + px + kx], w[ky * 3 + kx], s);
          acc[h][py * 2 + px] = s;
        }
    }
  }
  __syncthreads();
#pragma unroll
  for (int h = 0; h < HNUM; h++)
#pragma unroll
    for (int p = 0; p < 4; p++) {
      float v = floorf((acc[h][p] + b[h]) * 0.25f);
      v = fabsf(fmodf(v, (float)TSZ));
      atomicAdd(&hist[(h << 9) + (int)v], 1);
    }
  __syncthreads();
  for (int i = tid; i < HNUM * TSZ; i += 256) {
    int cv = hist[i];
    if (cv) atomicAdd(&counts[i], cv);
  }
}

// ---------------- K4: argmax per hash + mask (as float 0/1) ----------------
__global__ __launch_bounds__(512) void k_mask(
    const int* __restrict__ counts, const int* __restrict__ kbuck,
    float* __restrict__ maskf) {
  int tid = threadIdx.x;
  __shared__ int sv[HNUM];
  int h = tid >> 6, lane = tid & 63;
  // argmax with first-max tie-break: key = count*1024 + (511 - idx), count<2^20
  int best = -1;
  for (int i = lane; i < TSZ; i += 64) {
    int key = (counts[h * TSZ + i] << 10) | (TSZ - 1 - i);
    if (key > best) best = key;
  }
  for (int off = 32; off > 0; off >>= 1) {
    int other = __shfl_xor(best, off);
    if (other > best) best = other;
  }
  if (lane == 0) sv[h] = (TSZ - 1) - (best & 1023);
  __syncthreads();
  if (tid < OCH) {
    int m = 0;
    for (int hh = 0; hh < HNUM; hh++) {
      int kv = kbuck[hh * OCH + tid];
#pragma unroll
      for (int j = 0; j < HNUM; j++) m |= (kv == sv[j]) ? 1 : 0;
    }
    maskf[tid] = m ? 1.0f : 0.0f;
  }
}

// ---------------- K5: masked 3x3 conv as implicit GEMM, fp16 MFMA ----------------
// Block: 256 thr = 4 waves (2 och-halves x 2 rows). Out tile: 128 och x (2 rows x 64 cols).
// LDS X tile TRANSPOSED: [4 rows][8 kslots][66 cols] of f16x8 (16B) -> wave reads are
// contiguous 512B runs (bank-conflict-free), staged ONCE, K-loop has NO barriers.
// LDS = 33.8 KB -> 4 blocks/CU (16 waves/CU).
#define XCOLS 66

__global__ __launch_bounds__(256, 4) void k_conv_mfma(
    const float* __restrict__ x, const f16* __restrict__ wt,
    const float* __restrict__ maskf, float* __restrict__ out) {
  __shared__ f16x8 xs[4 * 8 * XCOLS];
  __shared__ float smaskf[OCH];

  int tid = threadIdx.x;
  int lane = tid & 63, wid = tid >> 6;
  int l31 = lane & 31, lh = lane >> 5;
  int wm = wid >> 1;      // och half within block (0..1)
  int wp = wid & 1;       // image row within pair (0..1)

  int nt = blockIdx.x;    // och tile (0..1)
  int py = blockIdx.y;    // 0..127: (rowpair 0..63) | (colhalf<<6)
  int n = blockIdx.z;     // batch
  int y0 = (py & 63) * 2;
  int x0 = (py >> 6) * 64;

  // ---- stage X: 4 rows x 66 cols x 64 ch fp16, transposed [r][kslot][col] ----
  const float* xn = x + (size_t)n * NCH * IMG2;
  for (int i = tid; i < 4 * XCOLS; i += 256) {
    int r = i / XCOLS, col = i - r * XCOLS;
    int yy = y0 - 1 + r, xx = x0 - 1 + col;
    bool ok = ((unsigned)yy < (unsigned)IMG) & ((unsigned)xx < (unsigned)IMG);
    const float* src = xn + ((size_t)(ok ? yy : 0) * IMG + (ok ? xx : 0));
#pragma unroll
    for (int ks = 0; ks < 8; ks++) {
      f16x8 hv;
#pragma unroll
      for (int q = 0; q < 8; q++) {
        float v = ok ? src[(size_t)(ks * 8 + q) * IMG2] : 0.f;
        hv[q] = (f16)v;
      }
      xs[(r * 8 + ks) * XCOLS + col] = hv;
    }
  }
  for (int i = tid; i < OCH; i += 256) smaskf[i] = maskf[i];
  __syncthreads();

  // ---- per-lane weight row pointers (A-operand: och = base + l31 + mi*32) ----
  int ochb = nt * 128 + wm * 64;
  const f16* pw0 = wt + (size_t)(ochb + l31) * NCH;
  const f16* pw1 = wt + (size_t)(ochb + 32 + l31) * NCH;

  f32x16 acc00 = (f32x16)0.0f, acc01 = (f32x16)0.0f;
  f32x16 acc10 = (f32x16)0.0f, acc11 = (f32x16)0.0f;

#pragma unroll
  for (int dy = 0; dy < 3; dy++) {
    int rb = wp + dy;
#pragma unroll
    for (int dx = 0; dx < 3; dx++) {
      int tap = dy * 3 + dx;
      size_t tof = (size_t)tap * (OCH * NCH);
      int colA = l31 + dx;               // 0..65; B col = colA+32
#pragma unroll
      for (int s = 0; s < 2; s++) {
#pragma unroll
        for (int kk = 0; kk < 2; kk++) {
          int cw = s * 32 + kk * 16 + lh * 8;
          int ks = s * 4 + kk * 2 + lh;
          f16x8 w0 = *(const f16x8*)(pw0 + tof + cw);
          f16x8 w1 = *(const f16x8*)(pw1 + tof + cw);
          int base = (rb * 8 + ks) * XCOLS;
          f16x8 xA = xs[base + colA];
          f16x8 xB = xs[base + colA + 32];
          acc00 = __builtin_amdgcn_mfma_f32_32x32x16_f16(w0, xA, acc00, 0, 0, 0);
          acc01 = __builtin_amdgcn_mfma_f32_32x32x16_f16(w0, xB, acc01, 0, 0, 0);
          acc10 = __builtin_amdgcn_mfma_f32_32x32x16_f16(w1, xA, acc10, 0, 0, 0);
          acc11 = __builtin_amdgcn_mfma_f32_32x32x16_f16(w1, xB, acc11, 0, 0, 0);
        }
      }
    }
  }

  // ---- masked store: D col = lane&31 = pixel, row = (reg&3)+8*(reg>>2)+4*lh = och ----
  float* outp = out + (size_t)n * OCH * IMG2;
  int yy = y0 + wp;
#pragma unroll
  for (int mi = 0; mi < 2; mi++) {
    int ob = ochb + mi * 32 + 4 * lh;
#pragma unroll
    for (int reg = 0; reg < 16; reg++) {
      int och = ob + (reg & 3) + 8 * (reg >> 2);
      float mv = smaskf[och];
      size_t rowoff = (size_t)och * IMG2 + (size_t)yy * IMG + x0 + l31;
      float vA = (mi == 0 ? acc00[reg] : acc10[reg]) * mv;
      float vB = (mi == 0 ? acc01[reg] : acc11[reg]) * mv;
      outp[rowoff] = vA;
      outp[rowoff + 32] = vB;
    }
  }
}

extern "C" void kernel_launch(void* const* d_in, const int* in_sizes, int n_in,
                              void* d_out, int out_size, void* d_ws, size_t ws_size,
                              hipStream_t stream) {
  const float* x = (const float*)d_in[0];
  const float* kernels = (const float*)d_in[1];
  const float* a = (const float*)d_in[2];
  const float* b = (const float*)d_in[3];
  float* out = (float*)d_out;

  char* ws = (char*)d_ws;
  int* scalemax = (int*)(ws + 0);          // 4 B
  int* kbuck    = (int*)(ws + 1024);       // 8192 B
  int* counts   = (int*)(ws + 10240);      // 16384 B
  float* maskf  = (float*)(ws + 26624);    // 1024 B
  f16* wt       = (f16*)(ws + 32768);      // 294912 B (end: 327680)

  k_wt<<<dim3(OCH), dim3(64), 0, stream>>>(kernels, wt, counts, scalemax);
  k_norms<<<dim3(OCH), dim3(64), 0, stream>>>(kernels, scalemax);
  k_table<<<dim3(OCH), dim3(512), 0, stream>>>(kernels, a, b, scalemax, kbuck);
  k_vote<<<dim3(4, 4, 32), dim3(256), 0, stream>>>(x, a, b, counts);
  k_mask<<<dim3(1), dim3(512), 0, stream>>>(counts, kbuck, maskf);
  k_conv_mfma<<<dim3(2, 128, 32), dim3(256), 0, stream>>>(x, wt, maskf, out);
}

// Round 3
// 999.800 us; speedup vs baseline: 3.8643x; 1.3311x over previous
//
#include <hip/hip_runtime.h>

// ALSH Conv: hash-table init + vote + mask + masked 3x3 conv via fp16 MFMA.
// x: [32,64,128,128] f32, kernels: [256,64,3,3] f32, a: [8,67,3,3] f32, b: [8] f32
// out: [32,256,128,128] f32. R=4, U=0.99, table=512.

#define NCH 64
#define OCH 256
#define HNUM 8
#define IMG 128
#define IMG2 (IMG * IMG)
#define TSZ 512
#define KROW 576      // 64*9
#define AROW 603      // 67*9
#define MPOW 27

typedef unsigned short u16;
typedef _Float16 f16;
typedef __attribute__((ext_vector_type(8))) _Float16 f16x8;
typedef __attribute__((ext_vector_type(16))) float f32x16;

// ---- K0: weight transform -> wt2[tap][ks(8)][och(256)][q(8)] fp16; zero counts ----
__global__ __launch_bounds__(64) void k_wt(
    const float* __restrict__ kernels, f16* __restrict__ wt,
    int* __restrict__ counts, int* __restrict__ scalemax) {
  int o = blockIdx.x;      // 0..255
  int c = threadIdx.x;     // 0..63 (input channel)
  int ks = c >> 3, q = c & 7;
  const float* kr = kernels + (size_t)o * KROW + (size_t)c * 9;
#pragma unroll
  for (int tap = 0; tap < 9; tap++)
    wt[(((size_t)tap * 8 + ks) * OCH + o) * 8 + q] = (f16)kr[tap];
  int gid = o * 64 + c;
  if (gid < HNUM * TSZ) counts[gid] = 0;
  if (gid == 0) *scalemax = 0;
}

// ---------------- K1: row-norm max via wave-cooperative reduce ----------------
__global__ __launch_bounds__(64) void k_norms(
    const float* __restrict__ kernels, int* __restrict__ scalemax) {
  int o = blockIdx.x, lane = threadIdx.x;
  const float* row = kernels + (size_t)o * KROW;
  float s = 0.f;
  for (int i = lane; i < KROW; i += 64) { float v = row[i]; s = fmaf(v, v, s); }
  for (int off = 32; off > 0; off >>= 1) s += __shfl_xor(s, off);
  if (lane == 0) atomicMax(scalemax, __float_as_int(sqrtf(s)));  // >0: int order ok
}

// ---------------- K2: kernel buckets, one wave per (o,h) ----------------
__global__ __launch_bounds__(512) void k_table(
    const float* __restrict__ kernels, const float* __restrict__ a,
    const float* __restrict__ b, const int* __restrict__ scalemax,
    int* __restrict__ kbuck) {
  int o = blockIdx.x;
  int h = threadIdx.x >> 6, lane = threadIdx.x & 63;
  float scale = 0.99f / __int_as_float(*scalemax);
  const float* ar = a + (size_t)h * AROW;
  const float* kr = kernels + (size_t)o * KROW;
  float dot = 0.f, s2 = 0.f;
  for (int i = lane; i < KROW; i += 64) {
    float sv = scale * kr[i];
    dot = fmaf(ar[i], sv, dot);
    s2 = fmaf(sv, sv, s2);
  }
  for (int off = 32; off > 0; off >>= 1) {
    dot += __shfl_xor(dot, off);
    s2 += __shfl_xor(s2, off);
  }
  if (lane == 0) {
    float p = sqrtf(s2), d = dot;
    for (int j = 1; j <= MPOW; j++) { p = p * p; d = fmaf(ar[KROW - 1 + j], p, d); }
    float v = floorf((d + b[h]) * 0.25f);
    v = fabsf(fmodf(v, (float)TSZ));
    kbuck[h * OCH + o] = (int)v;
  }
}

// ---- K3: vote conv + histogram. Barrier-free: no x tile, L1 serves halo. ----
// 1 px/thread; block = 4 rows x 64 cols; grid (2, 32, 32) = 2048 blocks.
__global__ __launch_bounds__(256) void k_vote(
    const float* __restrict__ x, const float* __restrict__ a,
    const float* __restrict__ b, int* __restrict__ counts) {
  int tid = threadIdx.x;
  int px = (blockIdx.x << 6) + (tid & 63);
  int py = (blockIdx.y << 2) + (tid >> 6);
  int n = blockIdx.z;

  __shared__ int hist[HNUM * TSZ];
  for (int i = tid; i < HNUM * TSZ; i += 256) hist[i] = 0;
  __syncthreads();

  // validity + safe (clamped, in-bounds) offsets, hoisted out of the c-loop
  bool vr0 = (py >= 1), vr2 = (py <= IMG - 2);          // wave-uniform
  bool vc0 = (px >= 1), vc2 = (px <= IMG - 2);          // per-lane
  int dyo0 = vr0 ? -IMG : 0, dyo2 = vr2 ? IMG : 0;
  int dxo0 = vc0 ? -1 : 0, dxo2 = vc2 ? 1 : 0;
  int off[9];
  off[0] = dyo0 + dxo0; off[1] = dyo0; off[2] = dyo0 + dxo2;
  off[3] = dxo0;        off[4] = 0;    off[5] = dxo2;
  off[6] = dyo2 + dxo0; off[7] = dyo2; off[8] = dyo2 + dxo2;
  bool ok[9];
  ok[0] = vr0 & vc0; ok[1] = vr0; ok[2] = vr0 & vc2;
  ok[3] = vc0;       ok[4] = true; ok[5] = vc2;
  ok[6] = vr2 & vc0; ok[7] = vr2; ok[8] = vr2 & vc2;

  const float* pc = x + (size_t)n * NCH * IMG2 + (size_t)py * IMG + px;
  float acc[HNUM] = {};

  for (int c = 0; c < NCH; c++) {
    float t[9];
#pragma unroll
    for (int k = 0; k < 9; k++) {
      float v = pc[off[k]];          // address always in-bounds (clamped)
      t[k] = ok[k] ? v : 0.f;
    }
#pragma unroll
    for (int h = 0; h < HNUM; h++) {
      const float* ww = a + (size_t)(h * 67 + c) * 9;  // block-uniform -> s_load
      float s = acc[h];
#pragma unroll
      for (int k = 0; k < 9; k++) s = fmaf(t[k], ww[k], s);
      acc[h] = s;
    }
    pc += IMG2;
  }
  // pad channels 64..66: constant 0.5 inside the image, 0 in conv padding
  {
    float t[9];
#pragma unroll
    for (int k = 0; k < 9; k++) t[k] = ok[k] ? 0.5f : 0.f;
#pragma unroll
    for (int h = 0; h < HNUM; h++) {
      float s = acc[h];
#pragma unroll
      for (int cc = 64; cc < 67; cc++) {
        const float* ww = a + (size_t)(h * 67 + cc) * 9;
#pragma unroll
        for (int k = 0; k < 9; k++) s = fmaf(t[k], ww[k], s);
      }
      acc[h] = s;
    }
  }
#pragma unroll
  for (int h = 0; h < HNUM; h++) {
    float v = floorf((acc[h] + b[h]) * 0.25f);
    v = fabsf(fmodf(v, (float)TSZ));
    atomicAdd(&hist[(h << 9) + (int)v], 1);
  }
  __syncthreads();
  for (int i = tid; i < HNUM * TSZ; i += 256) {
    int cv = hist[i];
    if (cv) atomicAdd(&counts[i], cv);
  }
}

// ---------------- K4: argmax per hash + mask (as float 0/1) ----------------
__global__ __launch_bounds__(512) void k_mask(
    const int* __restrict__ counts, const int* __restrict__ kbuck,
    float* __restrict__ maskf) {
  int tid = threadIdx.x;
  __shared__ int sv[HNUM];
  int h = tid >> 6, lane = tid & 63;
  int best = -1;
  for (int i = lane; i < TSZ; i += 64) {
    int key = (counts[h * TSZ + i] << 10) | (TSZ - 1 - i);
    if (key > best) best = key;
  }
  for (int off = 32; off > 0; off >>= 1) {
    int other = __shfl_xor(best, off);
    if (other > best) best = other;
  }
  if (lane == 0) sv[h] = (TSZ - 1) - (best & 1023);
  __syncthreads();
  if (tid < OCH) {
    int m = 0;
    for (int hh = 0; hh < HNUM; hh++) {
      int kv = kbuck[hh * OCH + tid];
#pragma unroll
      for (int j = 0; j < HNUM; j++) m |= (kv == sv[j]) ? 1 : 0;
    }
    maskf[tid] = m ? 1.0f : 0.0f;
  }
}

// ---------------- K5: masked 3x3 conv as implicit GEMM, fp16 MFMA ----------------
// Block 256 thr = 4 waves (2 och-halves x 2 rows); spatial tile = 2 rows x 128 cols.
// Each wave: M=64 och x N=128 px (4 B-frags) -> 8 MFMAs per (2 wt + 4 LDS) loads.
// nt-loop inside block covers all 256 och from ONE x staging. LDS x transposed
// [row][ks][col] -> contiguous conflict-free reads; K-loop has NO barriers.
// launch_bounds(256,2): 256 regs/lane (128 acc + prefetch headroom). 2 blocks/CU.
#define XCOLS 130

__global__ __launch_bounds__(256, 2) void k_conv_mfma(
    const float* __restrict__ x, const f16* __restrict__ wt,
    const float* __restrict__ maskf, float* __restrict__ out) {
  __shared__ f16x8 xs[4 * 8 * XCOLS];   // 66560 B
  __shared__ float smaskf[OCH];

  int tid = threadIdx.x;
  int lane = tid & 63, wid = tid >> 6;
  int l31 = lane & 31, lh = lane >> 5;
  int wm = wid >> 1;      // och 64-half within 128-group (0..1)
  int wp = wid & 1;       // image row within pair (0..1)

  int rp = blockIdx.x;    // row pair 0..63
  int n = blockIdx.y;     // batch
  int y0 = rp * 2;

  // ---- stage X once: 4 rows x 130 cols x 64 ch fp16, transposed [r][ks][col] ----
  const float* xn = x + (size_t)n * NCH * IMG2;
  for (int i = tid; i < 4 * XCOLS; i += 256) {
    int r = i / XCOLS, col = i - r * XCOLS;
    int yy = y0 - 1 + r, xx = col - 1;
    bool okb = ((unsigned)yy < (unsigned)IMG) & ((unsigned)xx < (unsigned)IMG);
    const float* src = xn + ((size_t)(okb ? yy : 0) * IMG + (okb ? xx : 0));
#pragma unroll
    for (int ks = 0; ks < 8; ks++) {
      f16x8 hv;
#pragma unroll
      for (int q = 0; q < 8; q++) {
        float v = okb ? src[(size_t)(ks * 8 + q) * IMG2] : 0.f;
        hv[q] = (f16)v;
      }
      xs[(r * 8 + ks) * XCOLS + col] = hv;
    }
  }
  for (int i = tid; i < OCH; i += 256) smaskf[i] = maskf[i];
  __syncthreads();

  float* outp = out + (size_t)n * OCH * IMG2;
  int yy = y0 + wp;

#pragma unroll 1
  for (int nt = 0; nt < 2; nt++) {
    int ochb = nt * 128 + wm * 64;
    f32x16 acc[2][4];
#pragma unroll
    for (int mi = 0; mi < 2; mi++)
#pragma unroll
      for (int nf = 0; nf < 4; nf++) acc[mi][nf] = (f32x16)0.0f;

#pragma unroll
    for (int dy = 0; dy < 3; dy++) {
#pragma unroll
      for (int dx = 0; dx < 3; dx++) {
        int tap = dy * 3 + dx;
#pragma unroll
        for (int s = 0; s < 2; s++) {
#pragma unroll
          for (int kk = 0; kk < 2; kk++) {
            int ks = s * 4 + kk * 2 + lh;
            // wt2 layout [tap][ks][och][8]: 32-lane read = contiguous 512 B
            const f16* wrow = wt + (((size_t)tap * 8 + ks) * OCH + ochb + l31) * 8;
            f16x8 w0 = *(const f16x8*)(wrow);
            f16x8 w1 = *(const f16x8*)(wrow + 32 * 8);
            int base = ((wp + dy) * 8 + ks) * XCOLS + l31 + dx;
            f16x8 x0 = xs[base];
            f16x8 x1 = xs[base + 32];
            f16x8 x2 = xs[base + 64];
            f16x8 x3 = xs[base + 96];
            acc[0][0] = __builtin_amdgcn_mfma_f32_32x32x16_f16(w0, x0, acc[0][0], 0, 0, 0);
            acc[0][1] = __builtin_amdgcn_mfma_f32_32x32x16_f16(w0, x1, acc[0][1], 0, 0, 0);
            acc[0][2] = __builtin_amdgcn_mfma_f32_32x32x16_f16(w0, x2, acc[0][2], 0, 0, 0);
            acc[0][3] = __builtin_amdgcn_mfma_f32_32x32x16_f16(w0, x3, acc[0][3], 0, 0, 0);
            acc[1][0] = __builtin_amdgcn_mfma_f32_32x32x16_f16(w1, x0, acc[1][0], 0, 0, 0);
            acc[1][1] = __builtin_amdgcn_mfma_f32_32x32x16_f16(w1, x1, acc[1][1], 0, 0, 0);
            acc[1][2] = __builtin_amdgcn_mfma_f32_32x32x16_f16(w1, x2, acc[1][2], 0, 0, 0);
            acc[1][3] = __builtin_amdgcn_mfma_f32_32x32x16_f16(w1, x3, acc[1][3], 0, 0, 0);
          }
        }
      }
    }

    // ---- masked store: D col = l31 = pixel, row = (reg&3)+8*(reg>>2)+4*lh = och ----
#pragma unroll
    for (int mi = 0; mi < 2; mi++) {
      int ob = ochb + mi * 32 + 4 * lh;
#pragma unroll
      for (int reg = 0; reg < 16; reg++) {
        int och = ob + (reg & 3) + 8 * (reg >> 2);
        float mv = smaskf[och];
        size_t rowoff = (size_t)och * IMG2 + (size_t)yy * IMG + l31;
#pragma unroll
        for (int nf = 0; nf < 4; nf++)
          outp[rowoff + nf * 32] = acc[mi][nf][reg] * mv;
      }
    }
  }
}

extern "C" void kernel_launch(void* const* d_in, const int* in_sizes, int n_in,
                              void* d_out, int out_size, void* d_ws, size_t ws_size,
                              hipStream_t stream) {
  const float* x = (const float*)d_in[0];
  const float* kernels = (const float*)d_in[1];
  const float* a = (const float*)d_in[2];
  const float* b = (const float*)d_in[3];
  float* out = (float*)d_out;

  char* ws = (char*)d_ws;
  int* scalemax = (int*)(ws + 0);          // 4 B
  int* kbuck    = (int*)(ws + 1024);       // 8192 B
  int* counts   = (int*)(ws + 10240);      // 16384 B
  float* maskf  = (float*)(ws + 26624);    // 1024 B
  f16* wt       = (f16*)(ws + 32768);      // 294912 B (end: 327680)

  k_wt<<<dim3(OCH), dim3(64), 0, stream>>>(kernels, wt, counts, scalemax);
  k_norms<<<dim3(OCH), dim3(64), 0, stream>>>(kernels, scalemax);
  k_table<<<dim3(OCH), dim3(512), 0, stream>>>(kernels, a, b, scalemax, kbuck);
  k_vote<<<dim3(2, 32, 32), dim3(256), 0, stream>>>(x, a, b, counts);
  k_mask<<<dim3(1), dim3(512), 0, stream>>>(counts, kbuck, maskf);
  k_conv_mfma<<<dim3(64, 32), dim3(256), 0, stream>>>(x, wt, maskf, out);
}